// Round 3
// baseline (418.722 us; speedup 1.0000x reference)
//
#include <hip/hip_runtime.h>
#include <hip/hip_bf16.h>

#define S_LEN 4096
#define DIN   256
#define DOUT  64
#define NBATCH 4
#define KB    64
#define NW    8   // waves per attn block

typedef __attribute__((ext_vector_type(8))) short short8;
typedef __attribute__((ext_vector_type(4))) float f32x4;

__device__ __forceinline__ ushort f2bf(float f) {
  union { float f; unsigned u; } c; c.f = f;
  unsigned u = c.u;
  u += 0x7fffu + ((u >> 16) & 1u);   // round-to-nearest-even
  return (ushort)(u >> 16);
}

// ---------------- fused projections: K, Q (scaled), V (transposed) ----------------
// grid (B*S/16, 3), 256 threads. y=0: K row-major; y=1: Q row-major * log2e/64; y=2: V -> Vt[b][64][S]
__global__ __launch_bounds__(256) void proj_all(
    const float* __restrict__ Xk, const float* __restrict__ Wk, ushort* __restrict__ Kb,
    const float* __restrict__ Xq, const float* __restrict__ Wq, ushort* __restrict__ Qb,
    const float* __restrict__ Xv, const float* __restrict__ Wv, ushort* __restrict__ Vt)
{
  __shared__ ushort tile[16][72];
  const int which = blockIdx.y;
  const float* X; const float* W;
  if (which == 0)      { X = Xk; W = Wk; }
  else if (which == 1) { X = Xq; W = Wq; }
  else                 { X = Xv; W = Wv; }

  const int lane = threadIdx.x & 63;
  const int wv   = threadIdx.x >> 6;
  const size_t row0 = (size_t)blockIdx.x * 16 + wv * 4;
  const float* x = X + row0 * DIN;
  float a0 = 0.f, a1 = 0.f, a2 = 0.f, a3 = 0.f;
#pragma unroll 4
  for (int k = 0; k < DIN; k += 4) {
    float4 x0 = *(const float4*)(x + k);
    float4 x1 = *(const float4*)(x + DIN + k);
    float4 x2 = *(const float4*)(x + 2 * DIN + k);
    float4 x3 = *(const float4*)(x + 3 * DIN + k);
    float w0 = W[(k + 0) * DOUT + lane];
    float w1 = W[(k + 1) * DOUT + lane];
    float w2 = W[(k + 2) * DOUT + lane];
    float w3 = W[(k + 3) * DOUT + lane];
    a0 += x0.x * w0 + x0.y * w1 + x0.z * w2 + x0.w * w3;
    a1 += x1.x * w0 + x1.y * w1 + x1.z * w2 + x1.w * w3;
    a2 += x2.x * w0 + x2.y * w1 + x2.z * w2 + x2.w * w3;
    a3 += x3.x * w0 + x3.y * w1 + x3.z * w2 + x3.w * w3;
  }
  if (which == 1) {
    const float qscale = 0.022542110016608813f;   // log2(e) / sqrt(4096)
    a0 *= qscale; a1 *= qscale; a2 *= qscale; a3 *= qscale;
  }
  if (which < 2) {
    ushort* O = (which == 0) ? Kb : Qb;
    ushort* o = O + row0 * DOUT + lane;
    o[0]        = f2bf(a0);
    o[DOUT]     = f2bf(a1);
    o[2 * DOUT] = f2bf(a2);
    o[3 * DOUT] = f2bf(a3);
  } else {
    const int r0 = wv * 4;
    tile[r0 + 0][lane] = f2bf(a0);
    tile[r0 + 1][lane] = f2bf(a1);
    tile[r0 + 2][lane] = f2bf(a2);
    tile[r0 + 3][lane] = f2bf(a3);
    __syncthreads();
    if (threadIdx.x < 64) {
      const int f = threadIdx.x;
      ushort v[16];
#pragma unroll
      for (int i = 0; i < 16; ++i) v[i] = tile[i][f];
      const size_t gr0 = (size_t)blockIdx.x * 16;
      const size_t b    = gr0 / S_LEN;
      const size_t srow = gr0 % S_LEN;
      ushort* dst = Vt + (b * DOUT + f) * S_LEN + srow;
      *(short8*)dst       = *(short8*)v;
      *(short8*)(dst + 8) = *((short8*)v + 1);
    }
  }
}

// ---------------- flash attention, causal, 16 Q-rows/block, 8 waves stripe KV ----------------
__global__ __launch_bounds__(512, 8) void attn_kernel(
    const ushort* __restrict__ Qb, const ushort* __restrict__ Kb,
    const ushort* __restrict__ Vt, float* __restrict__ Out)
{
  __shared__ ushort plds[NW][16][72];   // per-wave P transpose staging
  __shared__ float  mbuf[NW][16];
  __shared__ float  obuf[16][64];       // shared fp32 merge buffer
  __shared__ float  lsum[16];

  const int tid  = threadIdx.x;
  const int lane = tid & 63;
  const int w    = tid >> 6;
  const int l15  = lane & 15;
  const int hi   = lane >> 4;          // 0..3
  const int b    = blockIdx.y;
  const int qbase = ((int)gridDim.x - 1 - (int)blockIdx.x) * 16;   // heavy blocks first

  // zero merge buffers (no barrier needed until after the loop)
  for (int i = tid; i < 16 * 64; i += 512) ((float*)obuf)[i] = 0.f;
  if (tid < 16) lsum[tid] = 0.f;

  // Q A-fragments (Q is pre-scaled by log2e/64 in projection)
  const ushort* Qp = Qb + ((size_t)(b * S_LEN + qbase + l15)) * DOUT + hi * 8;
  short8 qA0 = *(const short8*)Qp;
  short8 qA1 = *(const short8*)(Qp + 32);

  float m[4], l[4];
  f32x4 acc[4];
#pragma unroll
  for (int r = 0; r < 4; ++r) { m[r] = -INFINITY; l[r] = 0.f; }
#pragma unroll
  for (int ft = 0; ft < 4; ++ft) acc[ft] = (f32x4){0.f, 0.f, 0.f, 0.f};

  const int ntiles = ((qbase + 15) >> 6) + 1;
  const ushort* Kbase = Kb + (size_t)b * S_LEN * DOUT;
  const ushort* Vbase = Vt + (size_t)b * DOUT * S_LEN;

  for (int t = w; t < ntiles; t += NW) {
    const int kv = t * KB;
    // --- QK^T (already in exp2 domain via pre-scaled Q) ---
    float lv[4][4];
#pragma unroll
    for (int sub = 0; sub < 4; ++sub) {
      const ushort* kp = Kbase + (size_t)(kv + sub * 16 + l15) * DOUT + hi * 8;
      short8 kf0 = *(const short8*)kp;
      short8 kf1 = *(const short8*)(kp + 32);
      f32x4 s = (f32x4){0.f, 0.f, 0.f, 0.f};
      s = __builtin_amdgcn_mfma_f32_16x16x32_bf16(qA0, kf0, s, 0, 0, 0);
      s = __builtin_amdgcn_mfma_f32_16x16x32_bf16(qA1, kf1, s, 0, 0, 0);
      const int kg = kv + sub * 16 + l15;
#pragma unroll
      for (int r = 0; r < 4; ++r) {
        const int qg = qbase + hi * 4 + r;
        lv[sub][r] = (kg > qg) ? -INFINITY : s[r];
      }
    }
    // --- row max (in-lane over 4 subtiles, then across 16 lanes) ---
    float tm[4], rs[4], sf[4], P[4][4];
#pragma unroll
    for (int r = 0; r < 4; ++r)
      tm[r] = fmaxf(fmaxf(lv[0][r], lv[1][r]), fmaxf(lv[2][r], lv[3][r]));
#pragma unroll
    for (int msk = 1; msk < 16; msk <<= 1)
#pragma unroll
      for (int r = 0; r < 4; ++r)
        tm[r] = fmaxf(tm[r], __shfl_xor(tm[r], msk, 64));
    // --- online-softmax update ---
#pragma unroll
    for (int r = 0; r < 4; ++r) {
      float mn = fmaxf(m[r], tm[r]);
      float msafe = (mn == -INFINITY) ? 0.f : mn;
      sf[r] = exp2f(m[r] - msafe);
      m[r] = mn;
      float s0 = 0.f;
#pragma unroll
      for (int sub = 0; sub < 4; ++sub) {
        float p = exp2f(lv[sub][r] - msafe);
        P[sub][r] = p;
        s0 += p;
      }
      rs[r] = s0;
    }
#pragma unroll
    for (int msk = 1; msk < 16; msk <<= 1)
#pragma unroll
      for (int r = 0; r < 4; ++r)
        rs[r] += __shfl_xor(rs[r], msk, 64);
#pragma unroll
    for (int r = 0; r < 4; ++r) {
      l[r] = l[r] * sf[r] + rs[r];
#pragma unroll
      for (int ft = 0; ft < 4; ++ft) acc[ft][r] *= sf[r];
    }
    // --- P -> bf16 via per-wave LDS region (no barrier) ---
#pragma unroll
    for (int sub = 0; sub < 4; ++sub)
#pragma unroll
      for (int r = 0; r < 4; ++r)
        plds[w][hi * 4 + r][sub * 16 + l15] = f2bf(P[sub][r]);
    // --- PV : O += P * V ---
#pragma unroll
    for (int ks = 0; ks < 2; ++ks) {
      short8 pA = *(const short8*)&plds[w][l15][ks * 32 + hi * 8];
#pragma unroll
      for (int ft = 0; ft < 4; ++ft) {
        const ushort* vp = Vbase + (size_t)(ft * 16 + l15) * S_LEN + kv + ks * 32 + hi * 8;
        short8 vB = *(const short8*)vp;
        acc[ft] = __builtin_amdgcn_mfma_f32_16x16x32_bf16(pA, vB, acc[ft], 0, 0, 0);
      }
    }
  }

  // --- merge the 8 KV-stripe waves ---
  if (l15 == 0) {
#pragma unroll
    for (int r = 0; r < 4; ++r) mbuf[w][hi * 4 + r] = m[r];
  }
  __syncthreads();

  float ew[4];
#pragma unroll
  for (int r = 0; r < 4; ++r) {
    const int row = hi * 4 + r;
    float M = mbuf[0][row];
#pragma unroll
    for (int i = 1; i < NW; ++i) M = fmaxf(M, mbuf[i][row]);
    ew[r] = exp2f(m[r] - M);            // m=-inf (empty stripe) -> 0, M always finite
    if (l15 == 0) atomicAdd(&lsum[row], l[r] * ew[r]);
  }
#pragma unroll
  for (int ft = 0; ft < 4; ++ft)
#pragma unroll
    for (int r = 0; r < 4; ++r)
      atomicAdd(&obuf[hi * 4 + r][ft * 16 + l15], acc[ft][r] * ew[r]);
  __syncthreads();

  if (tid < 256) {
    const int row = tid >> 4;
    const int cs  = (tid & 15) * 4;
    const float inv = 1.f / lsum[row];
    float4 o;
#pragma unroll
    for (int c = 0; c < 4; ++c) ((float*)&o)[c] = obuf[row][cs + c] * inv;
    *(float4*)(Out + ((size_t)(b * S_LEN + qbase + row)) * DOUT + cs) = o;
  }
}

extern "C" void kernel_launch(void* const* d_in, const int* in_sizes, int n_in,
                              void* d_out, int out_size, void* d_ws, size_t ws_size,
                              hipStream_t stream) {
  const float* Xk = (const float*)d_in[0];
  const float* Xv = (const float*)d_in[1];
  const float* Xq = (const float*)d_in[2];
  const float* Wk = (const float*)d_in[3];
  const float* Wv = (const float*)d_in[4];
  const float* Wq = (const float*)d_in[5];
  float* Out = (float*)d_out;

  ushort* Kb = (ushort*)d_ws;                               // [B][S][64] bf16
  ushort* Qb = Kb + (size_t)NBATCH * S_LEN * DOUT;          // [B][S][64] bf16 (pre-scaled)
  ushort* Vt = Qb + (size_t)NBATCH * S_LEN * DOUT;          // [B][64][S] bf16

  proj_all<<<dim3(NBATCH * S_LEN / 16, 3), 256, 0, stream>>>(Xk, Wk, Kb, Xq, Wq, Qb, Xv, Wv, Vt);
  attn_kernel<<<dim3(S_LEN / 16, NBATCH), 512, 0, stream>>>(Qb, Kb, Vt, Out);
}

// Round 4
// 215.160 us; speedup vs baseline: 1.9461x; 1.9461x over previous
//
#include <hip/hip_runtime.h>
#include <hip/hip_bf16.h>

#define S_LEN 4096
#define DIN   256
#define DOUT  64
#define NBATCH 4
#define NW    8     // waves per attn block
#define BKP   258   // padded k-stride (ushorts) for W^T in LDS

typedef __attribute__((ext_vector_type(8))) short short8;
typedef __attribute__((ext_vector_type(4))) float f32x4;

__device__ __forceinline__ ushort f2bf(float f) {
  union { float f; unsigned u; } c; c.f = f;
  unsigned u = c.u;
  u += 0x7fffu + ((u >> 16) & 1u);   // round-to-nearest-even
  return (ushort)(u >> 16);
}

// ---------------- projection GEMM: O = X(fp32)->bf16 @ W(fp32)->bf16 via MFMA ----------
// grid (M/64, 3), 256 threads. y=0: K row-major; y=1: Q row-major * log2e/64;
// y=2: V -> Vt[b][64][S] with sigma-permuted row order within each 64-tile.
__global__ __launch_bounds__(256) void proj_kernel(
    const float* __restrict__ Xk, const float* __restrict__ Wk, ushort* __restrict__ Kb,
    const float* __restrict__ Xq, const float* __restrict__ Wq, ushort* __restrict__ Qb,
    const float* __restrict__ Xv, const float* __restrict__ Wv, ushort* __restrict__ Vt)
{
  __shared__ ushort Wt[DOUT][BKP];      // W^T bf16: [n][k], ~33 KB
  const int tid = threadIdx.x;
  const int which = blockIdx.y;
  const float* X = (which == 0) ? Xk : (which == 1) ? Xq : Xv;
  const float* W = (which == 0) ? Wk : (which == 1) ? Wq : Wv;

  // stage W^T as bf16 (coalesced float4 reads, one-time)
#pragma unroll
  for (int jj = 0; jj < 16; ++jj) {
    const int i4 = (jj * 256 + tid) * 4;        // flat float idx, 4-aligned
    float4 w4 = *(const float4*)(W + i4);
    const int k = i4 >> 6;
    const int n = i4 & 63;
    Wt[n + 0][k] = f2bf(w4.x);
    Wt[n + 1][k] = f2bf(w4.y);
    Wt[n + 2][k] = f2bf(w4.z);
    Wt[n + 3][k] = f2bf(w4.w);
  }
  __syncthreads();

  const int lane = tid & 63, w = tid >> 6;
  const int l15 = lane & 15, hi = lane >> 4;
  const size_t gr0 = (size_t)blockIdx.x * 64;   // 64 rows per block
  const int rowbase = w * 16;                   // 16 rows per wave
  const float* xrow = X + (gr0 + rowbase + l15) * DIN;

  f32x4 acc[4];
#pragma unroll
  for (int ft = 0; ft < 4; ++ft) acc[ft] = (f32x4){0.f, 0.f, 0.f, 0.f};

#pragma unroll
  for (int ks = 0; ks < 8; ++ks) {
    float4 xa = *(const float4*)(xrow + ks * 32 + hi * 8);
    float4 xb = *(const float4*)(xrow + ks * 32 + hi * 8 + 4);
    ushort af[8];
    af[0] = f2bf(xa.x); af[1] = f2bf(xa.y); af[2] = f2bf(xa.z); af[3] = f2bf(xa.w);
    af[4] = f2bf(xb.x); af[5] = f2bf(xb.y); af[6] = f2bf(xb.z); af[7] = f2bf(xb.w);
    short8 A = *(short8*)af;
#pragma unroll
    for (int ft = 0; ft < 4; ++ft) {
      short8 Bf = *(const short8*)&Wt[ft * 16 + l15][ks * 32 + hi * 8];
      acc[ft] = __builtin_amdgcn_mfma_f32_16x16x32_bf16(A, Bf, acc[ft], 0, 0, 0);
    }
  }

  if (which < 2) {
    ushort* O = (which == 0) ? Kb : Qb;
    const float qs = (which == 1) ? 0.022542110016608813f : 1.0f;  // log2(e)/sqrt(4096)
#pragma unroll
    for (int ft = 0; ft < 4; ++ft)
#pragma unroll
      for (int r = 0; r < 4; ++r)
        O[(gr0 + rowbase + 4 * hi + r) * DOUT + ft * 16 + l15] = f2bf(acc[ft][r] * qs);
  } else {
    const size_t b     = gr0 >> 12;       // / 4096
    const size_t sbase = gr0 & 4095;      // 64-aligned within batch
#pragma unroll
    for (int ft = 0; ft < 4; ++ft) {
      const int n = ft * 16 + l15;
      ushort* dst = Vt + (b * DOUT + n) * S_LEN + sbase;
#pragma unroll
      for (int r = 0; r < 4; ++r) {
        const int s = rowbase + 4 * hi + r;                        // 0..63 original key
        const int slot = (s & 0x23) | ((s & 0x10) >> 2) | ((s & 0x0C) << 1);  // sigma^-1
        dst[slot] = f2bf(acc[ft][r]);
      }
    }
  }
}

// ---------------- flash attention, swapped QK^T, in-register P, 8 waves stripe KV ------
__global__ __launch_bounds__(512, 4) void attn_kernel(
    const ushort* __restrict__ Qb, const ushort* __restrict__ Kb,
    const ushort* __restrict__ Vt, float* __restrict__ Out)
{
  __shared__ float mbuf[NW][16];
  __shared__ float Mmax[16];
  __shared__ float lsum[16];
  __shared__ float obuf[16][64];

  const int tid  = threadIdx.x;
  const int lane = tid & 63;
  const int w    = tid >> 6;
  const int l15  = lane & 15;
  const int hi   = lane >> 4;          // 0..3
  const int b    = blockIdx.y;
  const int qbase = ((int)gridDim.x - 1 - (int)blockIdx.x) * 16;   // heavy blocks first

  for (int i = tid; i < 16 * 64; i += 512) ((float*)obuf)[i] = 0.f;
  if (tid < 16) lsum[tid] = 0.f;

  // Q as B-operand fragments (pre-scaled by log2e/64): col=q=l15, depth=8*hi..+7
  const ushort* Qp = Qb + ((size_t)b * S_LEN + qbase + l15) * DOUT + hi * 8;
  short8 qB0 = *(const short8*)Qp;
  short8 qB1 = *(const short8*)(Qp + 32);

  float m = -INFINITY, l = 0.f;        // per-lane softmax state for row q = qbase+l15
  f32x4 acc[4];                        // O[q=4hi+r][dout=ft*16+l15]
#pragma unroll
  for (int ft = 0; ft < 4; ++ft) acc[ft] = (f32x4){0.f, 0.f, 0.f, 0.f};

  const int ntiles = ((qbase + 15) >> 6) + 1;
  const ushort* Kbase = Kb + (size_t)b * S_LEN * DOUT;
  const ushort* Vbase = Vt + (size_t)b * DOUT * S_LEN;
  const int qg = qbase + l15;

  for (int t = w; t < ntiles; t += NW) {
    const int kv = t * 64;
    float p[4][4];                     // p[sub][r]: key = kv+16*sub+4*hi+r, q = l15
    // --- QK^T swapped: A=K, B=Q -> C[key][q] ---
#pragma unroll
    for (int sub = 0; sub < 4; ++sub) {
      const ushort* kp = Kbase + (size_t)(kv + sub * 16 + l15) * DOUT + hi * 8;
      short8 kf0 = *(const short8*)kp;
      short8 kf1 = *(const short8*)(kp + 32);
      f32x4 s = (f32x4){0.f, 0.f, 0.f, 0.f};
      s = __builtin_amdgcn_mfma_f32_16x16x32_bf16(kf0, qB0, s, 0, 0, 0);
      s = __builtin_amdgcn_mfma_f32_16x16x32_bf16(kf1, qB1, s, 0, 0, 0);
#pragma unroll
      for (int r = 0; r < 4; ++r) p[sub][r] = s[r];
    }
    // --- causal mask: only the diagonal tile needs it ---
    if (t == ntiles - 1) {
#pragma unroll
      for (int sub = 0; sub < 4; ++sub)
#pragma unroll
        for (int r = 0; r < 4; ++r) {
          const int kg = kv + sub * 16 + 4 * hi + r;
          if (kg > qg) p[sub][r] = -INFINITY;
        }
    }
    // --- row max: 15 in-lane + 2 shuffles ---
    float tm = p[0][0];
#pragma unroll
    for (int sub = 0; sub < 4; ++sub)
#pragma unroll
      for (int r = 0; r < 4; ++r) tm = fmaxf(tm, p[sub][r]);
    tm = fmaxf(tm, __shfl_xor(tm, 16, 64));
    tm = fmaxf(tm, __shfl_xor(tm, 32, 64));
    // --- defer-max: rescale only when max grows beyond threshold ---
    if (!__all(tm <= m + 8.0f)) {
      const float mn = fmaxf(m, tm);
      const float sf = exp2f(m - mn);   // m=-inf -> 0
      m = mn;
      l *= sf;
      float sfr[4];
#pragma unroll
      for (int r = 0; r < 4; ++r) sfr[r] = __shfl(sf, 4 * hi + r, 64);
#pragma unroll
      for (int ft = 0; ft < 4; ++ft)
#pragma unroll
        for (int r = 0; r < 4; ++r) acc[ft][r] *= sfr[r];
    }
    // --- P = exp2(s - m), row sum: in-lane + 2 shuffles ---
    float rs = 0.f;
#pragma unroll
    for (int sub = 0; sub < 4; ++sub)
#pragma unroll
      for (int r = 0; r < 4; ++r) {
        const float e = exp2f(p[sub][r] - m);
        p[sub][r] = e;
        rs += e;
      }
    rs += __shfl_xor(rs, 16, 64);
    rs += __shfl_xor(rs, 32, 64);
    l += rs;
    // --- pack P into PV A-fragments (sigma-permuted V makes this lane-local) ---
    ushort pk[16];
#pragma unroll
    for (int sub = 0; sub < 4; ++sub)
#pragma unroll
      for (int r = 0; r < 4; ++r) pk[sub * 4 + r] = f2bf(p[sub][r]);
    short8 pa0 = *(short8*)pk;
    short8 pa1 = *((short8*)pk + 1);
    // --- PV: A=P[q][slot], B=V_perm[slot][dout] ---
#pragma unroll
    for (int ft = 0; ft < 4; ++ft) {
      const ushort* vp = Vbase + (size_t)(ft * 16 + l15) * S_LEN + kv + hi * 8;
      short8 vb0 = *(const short8*)vp;
      short8 vb1 = *(const short8*)(vp + 32);
      acc[ft] = __builtin_amdgcn_mfma_f32_16x16x32_bf16(pa0, vb0, acc[ft], 0, 0, 0);
      acc[ft] = __builtin_amdgcn_mfma_f32_16x16x32_bf16(pa1, vb1, acc[ft], 0, 0, 0);
    }
  }

  // --- merge the 8 KV-stripe waves ---
  if (lane < 16) mbuf[w][lane] = m;
  __syncthreads();
  if (tid < 16) {
    float M = mbuf[0][tid];
#pragma unroll
    for (int i = 1; i < NW; ++i) M = fmaxf(M, mbuf[i][tid]);
    Mmax[tid] = M;
  }
  __syncthreads();
  if (lane < 16) atomicAdd(&lsum[l15], l * exp2f(m - Mmax[l15]));
  float ew[4];
#pragma unroll
  for (int r = 0; r < 4; ++r) ew[r] = exp2f(mbuf[w][4 * hi + r] - Mmax[4 * hi + r]);
#pragma unroll
  for (int ft = 0; ft < 4; ++ft)
#pragma unroll
    for (int r = 0; r < 4; ++r)
      atomicAdd(&obuf[4 * hi + r][ft * 16 + l15], acc[ft][r] * ew[r]);
  __syncthreads();

  if (tid < 256) {
    const int row = tid >> 4;
    const int cs  = (tid & 15) * 4;
    const float inv = 1.f / lsum[row];
    float4 o;
#pragma unroll
    for (int c = 0; c < 4; ++c) ((float*)&o)[c] = obuf[row][cs + c] * inv;
    *(float4*)(Out + ((size_t)b * S_LEN + qbase + row) * DOUT + cs) = o;
  }
}

extern "C" void kernel_launch(void* const* d_in, const int* in_sizes, int n_in,
                              void* d_out, int out_size, void* d_ws, size_t ws_size,
                              hipStream_t stream) {
  const float* Xk = (const float*)d_in[0];
  const float* Xv = (const float*)d_in[1];
  const float* Xq = (const float*)d_in[2];
  const float* Wk = (const float*)d_in[3];
  const float* Wv = (const float*)d_in[4];
  const float* Wq = (const float*)d_in[5];
  float* Out = (float*)d_out;

  ushort* Kb = (ushort*)d_ws;                               // [B][S][64] bf16
  ushort* Qb = Kb + (size_t)NBATCH * S_LEN * DOUT;          // [B][S][64] bf16 (pre-scaled)
  ushort* Vt = Qb + (size_t)NBATCH * S_LEN * DOUT;          // [B][64][S] bf16, sigma-permuted

  proj_kernel<<<dim3(NBATCH * S_LEN / 64, 3), 256, 0, stream>>>(
      Xk, Wk, Kb, Xq, Wq, Qb, Xv, Wv, Vt);
  attn_kernel<<<dim3(S_LEN / 16, NBATCH), 512, 0, stream>>>(Qb, Kb, Vt, Out);
}

// Round 6
// 209.922 us; speedup vs baseline: 1.9947x; 1.0250x over previous
//
#include <hip/hip_runtime.h>
#include <hip/hip_bf16.h>

#define S_LEN 4096
#define DIN   256
#define DOUT  64
#define NBATCH 4
#define NW    4     // waves per attn block
#define KB    32    // keys per tile
#define BKP   258   // padded k-stride (ushorts) for W^T in LDS

typedef __attribute__((ext_vector_type(8))) short short8;
typedef __attribute__((ext_vector_type(4))) float f32x4;

__device__ __forceinline__ ushort f2bf(float f) {
  union { float f; unsigned u; } c; c.f = f;
  unsigned u = c.u;
  u += 0x7fffu + ((u >> 16) & 1u);   // round-to-nearest-even
  return (ushort)(u >> 16);
}

// ---------------- projection GEMM: O = X(fp32)->bf16 @ W(fp32)->bf16 via MFMA ----------
// grid (M/64, 3), 256 threads. y=0: K row-major; y=1: Q row-major * log2e/64;
// y=2: V -> Vt[b][64][S] with sigma-permuted row order within each 32-tile.
__global__ __launch_bounds__(256) void proj_kernel(
    const float* __restrict__ Xk, const float* __restrict__ Wk, ushort* __restrict__ Kb,
    const float* __restrict__ Xq, const float* __restrict__ Wq, ushort* __restrict__ Qb,
    const float* __restrict__ Xv, const float* __restrict__ Wv, ushort* __restrict__ Vt)
{
  __shared__ ushort Wt[DOUT][BKP];      // W^T bf16: [n][k], ~33 KB
  const int tid = threadIdx.x;
  const int which = blockIdx.y;
  const float* X = (which == 0) ? Xk : (which == 1) ? Xq : Xv;
  const float* W = (which == 0) ? Wk : (which == 1) ? Wq : Wv;

  // stage W^T as bf16 (coalesced float4 reads, one-time)
#pragma unroll
  for (int jj = 0; jj < 16; ++jj) {
    const int i4 = (jj * 256 + tid) * 4;        // flat float idx, 4-aligned
    float4 w4 = *(const float4*)(W + i4);
    const int k = i4 >> 6;
    const int n = i4 & 63;
    Wt[n + 0][k] = f2bf(w4.x);
    Wt[n + 1][k] = f2bf(w4.y);
    Wt[n + 2][k] = f2bf(w4.z);
    Wt[n + 3][k] = f2bf(w4.w);
  }
  __syncthreads();

  const int lane = tid & 63, w = tid >> 6;
  const int l15 = lane & 15, hi = lane >> 4;
  const size_t gr0 = (size_t)blockIdx.x * 64;   // 64 rows per block
  const int rowbase = w * 16;                   // 16 rows per wave
  const float* xrow = X + (gr0 + rowbase + l15) * DIN;

  f32x4 acc[4];
#pragma unroll
  for (int ft = 0; ft < 4; ++ft) acc[ft] = (f32x4){0.f, 0.f, 0.f, 0.f};

#pragma unroll
  for (int ks = 0; ks < 8; ++ks) {
    float4 xa = *(const float4*)(xrow + ks * 32 + hi * 8);
    float4 xb = *(const float4*)(xrow + ks * 32 + hi * 8 + 4);
    ushort af[8];
    af[0] = f2bf(xa.x); af[1] = f2bf(xa.y); af[2] = f2bf(xa.z); af[3] = f2bf(xa.w);
    af[4] = f2bf(xb.x); af[5] = f2bf(xb.y); af[6] = f2bf(xb.z); af[7] = f2bf(xb.w);
    short8 A = *(short8*)af;
#pragma unroll
    for (int ft = 0; ft < 4; ++ft) {
      short8 Bf = *(const short8*)&Wt[ft * 16 + l15][ks * 32 + hi * 8];
      acc[ft] = __builtin_amdgcn_mfma_f32_16x16x32_bf16(A, Bf, acc[ft], 0, 0, 0);
    }
  }

  if (which < 2) {
    ushort* O = (which == 0) ? Kb : Qb;
    const float qs = (which == 1) ? 0.022542110016608813f : 1.0f;  // log2(e)/sqrt(4096)
#pragma unroll
    for (int ft = 0; ft < 4; ++ft)
#pragma unroll
      for (int r = 0; r < 4; ++r)
        O[(gr0 + rowbase + 4 * hi + r) * DOUT + ft * 16 + l15] = f2bf(acc[ft][r] * qs);
  } else {
    const size_t b     = gr0 >> 12;       // / 4096
    const size_t sbase = gr0 & 4095;      // 64-aligned within batch
#pragma unroll
    for (int ft = 0; ft < 4; ++ft) {
      const int n = ft * 16 + l15;
      ushort* dst = Vt + (b * DOUT + n) * S_LEN + sbase;
#pragma unroll
      for (int r = 0; r < 4; ++r) {
        const int s = rowbase + 4 * hi + r;                        // 0..63 original key
        const int slot = (s & 0x23) | ((s & 0x10) >> 2) | ((s & 0x0C) << 1);  // sigma^-1 (within each 32)
        dst[slot] = f2bf(acc[ft][r]);
      }
    }
  }
}

// ---------------- flash attention, swapped QK^T, software-pipelined, 4 waves stripe KV ----
__global__ __launch_bounds__(256) void attn_kernel(
    const ushort* __restrict__ Qb, const ushort* __restrict__ Kb,
    const ushort* __restrict__ Vt, float* __restrict__ Out)
{
  __shared__ float mbuf[NW][16];
  __shared__ float lbuf[NW][16];
  __shared__ float obuf[NW][16][64];

  const int tid  = threadIdx.x;
  const int lane = tid & 63;
  const int w    = tid >> 6;
  const int l15  = lane & 15;
  const int hi   = lane >> 4;          // 0..3
  const int b    = blockIdx.y;
  const int qbase = ((int)gridDim.x - 1 - (int)blockIdx.x) * 16;   // heavy blocks first

  // Q as B-operand fragments (pre-scaled by log2e/64): col=q=l15, depth=8*hi..+7
  const ushort* Qp = Qb + ((size_t)b * S_LEN + qbase + l15) * DOUT + hi * 8;
  short8 qB0 = *(const short8*)Qp;
  short8 qB1 = *(const short8*)(Qp + 32);

  float m = -INFINITY, l = 0.f;        // per-lane softmax state for row q = qbase+l15
  f32x4 acc[4];                        // O[q=4hi+r][dout=ft*16+l15]
#pragma unroll
  for (int ft = 0; ft < 4; ++ft) acc[ft] = (f32x4){0.f, 0.f, 0.f, 0.f};

  const int ntiles = qbase / KB + 1;
  const ushort* Kbase = Kb + (size_t)b * S_LEN * DOUT;
  const ushort* Vbase = Vt + (size_t)b * DOUT * S_LEN;
  const int qg = qbase + l15;

  // prologue: load K for this wave's first tile
  short8 ka[2][2];
  {
    const int kv0 = w * KB;
#pragma unroll
    for (int sub = 0; sub < 2; ++sub) {
      const ushort* kp = Kbase + (size_t)(kv0 + sub * 16 + l15) * DOUT + hi * 8;
      ka[sub][0] = *(const short8*)kp;
      ka[sub][1] = *(const short8*)(kp + 32);
    }
  }

#pragma unroll 2
  for (int t = w; t < ntiles; t += NW) {
    const int kv = t * KB;
    // --- issue V loads for current tile (consumed after softmax) ---
    short8 vb[4];
#pragma unroll
    for (int ft = 0; ft < 4; ++ft)
      vb[ft] = *(const short8*)(Vbase + (size_t)(ft * 16 + l15) * S_LEN + kv + hi * 8);
    // --- issue K prefetch for next stripe tile (consumed next iteration) ---
    const int tn = (t + NW < ntiles) ? (t + NW) : t;
    const int kvn = tn * KB;
    short8 kn[2][2];
#pragma unroll
    for (int sub = 0; sub < 2; ++sub) {
      const ushort* kp = Kbase + (size_t)(kvn + sub * 16 + l15) * DOUT + hi * 8;
      kn[sub][0] = *(const short8*)kp;
      kn[sub][1] = *(const short8*)(kp + 32);
    }
    // --- QK^T swapped: A=K, B=Q -> C[key][q]; K already in registers ---
    float p[2][4];                     // p[sub][r]: key = kv+16*sub+4*hi+r, q = l15
#pragma unroll
    for (int sub = 0; sub < 2; ++sub) {
      f32x4 s = (f32x4){0.f, 0.f, 0.f, 0.f};
      s = __builtin_amdgcn_mfma_f32_16x16x32_bf16(ka[sub][0], qB0, s, 0, 0, 0);
      s = __builtin_amdgcn_mfma_f32_16x16x32_bf16(ka[sub][1], qB1, s, 0, 0, 0);
#pragma unroll
      for (int r = 0; r < 4; ++r) p[sub][r] = s[r];
    }
    // --- causal mask: only the diagonal tile needs it ---
    if (t == ntiles - 1) {
#pragma unroll
      for (int sub = 0; sub < 2; ++sub)
#pragma unroll
        for (int r = 0; r < 4; ++r) {
          const int kg = kv + sub * 16 + 4 * hi + r;
          if (kg > qg) p[sub][r] = -INFINITY;
        }
    }
    // --- row max: 7 in-lane + 2 shuffles ---
    float tm = p[0][0];
#pragma unroll
    for (int sub = 0; sub < 2; ++sub)
#pragma unroll
      for (int r = 0; r < 4; ++r) tm = fmaxf(tm, p[sub][r]);
    tm = fmaxf(tm, __shfl_xor(tm, 16, 64));
    tm = fmaxf(tm, __shfl_xor(tm, 32, 64));
    // --- defer-max: rescale only when max grows beyond threshold ---
    if (!__all(tm <= m + 8.0f)) {
      const float mn = fmaxf(m, tm);
      const float sf = exp2f(m - mn);   // m=-inf -> 0
      m = mn;
      l *= sf;
      float sfr[4];
#pragma unroll
      for (int r = 0; r < 4; ++r) sfr[r] = __shfl(sf, 4 * hi + r, 64);
#pragma unroll
      for (int ft = 0; ft < 4; ++ft)
#pragma unroll
        for (int r = 0; r < 4; ++r) acc[ft][r] *= sfr[r];
    }
    // --- P = exp2(s - m), row sum: in-lane + 2 shuffles ---
    float rs = 0.f;
    ushort pk[8];
#pragma unroll
    for (int sub = 0; sub < 2; ++sub)
#pragma unroll
      for (int r = 0; r < 4; ++r) {
        const float e = exp2f(p[sub][r] - m);
        pk[sub * 4 + r] = f2bf(e);
        rs += e;
      }
    rs += __shfl_xor(rs, 16, 64);
    rs += __shfl_xor(rs, 32, 64);
    l += rs;
    short8 pa = *(short8*)pk;
    // --- PV: A=P[q][slot], B=V_perm[slot][dout] ---
#pragma unroll
    for (int ft = 0; ft < 4; ++ft)
      acc[ft] = __builtin_amdgcn_mfma_f32_16x16x32_bf16(pa, vb[ft], acc[ft], 0, 0, 0);
    // --- rotate prefetched K ---
#pragma unroll
    for (int sub = 0; sub < 2; ++sub) {
      ka[sub][0] = kn[sub][0];
      ka[sub][1] = kn[sub][1];
    }
  }

  // --- merge the 4 KV-stripe waves (no atomics) ---
  if (lane < 16) { mbuf[w][lane] = m; lbuf[w][lane] = l; }
#pragma unroll
  for (int ft = 0; ft < 4; ++ft)
#pragma unroll
    for (int r = 0; r < 4; ++r)
      obuf[w][4 * hi + r][ft * 16 + l15] = acc[ft][r];
  __syncthreads();

  const int row = tid >> 4;        // 0..15
  const int cs  = (tid & 15) * 4;  // 4 output cols per thread
  float mw[NW], ew[NW];
  float M = -INFINITY;
#pragma unroll
  for (int i = 0; i < NW; ++i) { mw[i] = mbuf[i][row]; M = fmaxf(M, mw[i]); }
  float L = 0.f;
#pragma unroll
  for (int i = 0; i < NW; ++i) { ew[i] = exp2f(mw[i] - M); L += lbuf[i][row] * ew[i]; }
  const float inv = 1.f / L;
  float4 o;
#pragma unroll
  for (int c = 0; c < 4; ++c) {
    float a = 0.f;
#pragma unroll
    for (int i = 0; i < NW; ++i) a += obuf[i][row][cs + c] * ew[i];
    ((float*)&o)[c] = a * inv;
  }
  *(float4*)(Out + ((size_t)b * S_LEN + qbase + row) * DOUT + cs) = o;
}

extern "C" void kernel_launch(void* const* d_in, const int* in_sizes, int n_in,
                              void* d_out, int out_size, void* d_ws, size_t ws_size,
                              hipStream_t stream) {
  const float* Xk = (const float*)d_in[0];
  const float* Xv = (const float*)d_in[1];
  const float* Xq = (const float*)d_in[2];
  const float* Wk = (const float*)d_in[3];
  const float* Wv = (const float*)d_in[4];
  const float* Wq = (const float*)d_in[5];
  float* Out = (float*)d_out;

  ushort* Kb = (ushort*)d_ws;                               // [B][S][64] bf16
  ushort* Qb = Kb + (size_t)NBATCH * S_LEN * DOUT;          // [B][S][64] bf16 (pre-scaled)
  ushort* Vt = Qb + (size_t)NBATCH * S_LEN * DOUT;          // [B][64][S] bf16, sigma-permuted

  proj_kernel<<<dim3(NBATCH * S_LEN / 64, 3), 256, 0, stream>>>(
      Xk, Wk, Kb, Xq, Wq, Qb, Xv, Wv, Vt);
  attn_kernel<<<dim3(S_LEN / 16, NBATCH), 256, 0, stream>>>(Qb, Kb, Vt, Out);
}

// Round 15
// 158.892 us; speedup vs baseline: 2.6353x; 1.3212x over previous
//
#include <hip/hip_runtime.h>
#include <hip/hip_bf16.h>

#define S_LEN 4096
#define DIN   256
#define DOUT  64
#define NBATCH 4
#define KB    32    // keys per tile
#define BKP   258   // padded k-stride (ushorts) for W^T in LDS

typedef __attribute__((ext_vector_type(8))) short short8;
typedef __attribute__((ext_vector_type(4))) float f32x4;

__device__ __forceinline__ ushort f2bf(float f) {
  union { float f; unsigned u; } c; c.f = f;
  unsigned u = c.u;
  u += 0x7fffu + ((u >> 16) & 1u);   // round-to-nearest-even
  return (ushort)(u >> 16);
}

// ---------------- projection GEMM: O = X(fp32)->bf16 @ W(fp32)->bf16 via MFMA ----------
// grid (M/64, 3), 256 threads. y=0: K row-major; y=1: Q row-major * log2e/64;
// y=2: V -> Vt[b][64][S] with sigma-permuted row order within each 32-tile.
__global__ __launch_bounds__(256) void proj_kernel(
    const float* __restrict__ Xk, const float* __restrict__ Wk, ushort* __restrict__ Kb,
    const float* __restrict__ Xq, const float* __restrict__ Wq, ushort* __restrict__ Qb,
    const float* __restrict__ Xv, const float* __restrict__ Wv, ushort* __restrict__ Vt)
{
  __shared__ ushort Wt[DOUT][BKP];      // W^T bf16: [n][k], ~33 KB
  const int tid = threadIdx.x;
  const int which = blockIdx.y;
  const float* X = (which == 0) ? Xk : (which == 1) ? Xq : Xv;
  const float* W = (which == 0) ? Wk : (which == 1) ? Wq : Wv;

  // stage W^T as bf16 (coalesced float4 reads, one-time)
#pragma unroll
  for (int jj = 0; jj < 16; ++jj) {
    const int i4 = (jj * 256 + tid) * 4;        // flat float idx, 4-aligned
    float4 w4 = *(const float4*)(W + i4);
    const int k = i4 >> 6;
    const int n = i4 & 63;
    Wt[n + 0][k] = f2bf(w4.x);
    Wt[n + 1][k] = f2bf(w4.y);
    Wt[n + 2][k] = f2bf(w4.z);
    Wt[n + 3][k] = f2bf(w4.w);
  }
  __syncthreads();

  const int lane = tid & 63, w = tid >> 6;
  const int l15 = lane & 15, hi = lane >> 4;
  const size_t gr0 = (size_t)blockIdx.x * 64;   // 64 rows per block
  const int rowbase = w * 16;                   // 16 rows per wave
  const float* xrow = X + (gr0 + rowbase + l15) * DIN;

  f32x4 acc[4];
#pragma unroll
  for (int ft = 0; ft < 4; ++ft) acc[ft] = (f32x4){0.f, 0.f, 0.f, 0.f};

#pragma unroll
  for (int ks = 0; ks < 8; ++ks) {
    float4 xa = *(const float4*)(xrow + ks * 32 + hi * 8);
    float4 xb = *(const float4*)(xrow + ks * 32 + hi * 8 + 4);
    ushort af[8];
    af[0] = f2bf(xa.x); af[1] = f2bf(xa.y); af[2] = f2bf(xa.z); af[3] = f2bf(xa.w);
    af[4] = f2bf(xb.x); af[5] = f2bf(xb.y); af[6] = f2bf(xb.z); af[7] = f2bf(xb.w);
    short8 A = *(short8*)af;
#pragma unroll
    for (int ft = 0; ft < 4; ++ft) {
      short8 Bf = *(const short8*)&Wt[ft * 16 + l15][ks * 32 + hi * 8];
      acc[ft] = __builtin_amdgcn_mfma_f32_16x16x32_bf16(A, Bf, acc[ft], 0, 0, 0);
    }
  }

  if (which < 2) {
    ushort* O = (which == 0) ? Kb : Qb;
    const float qs = (which == 1) ? 0.022542110016608813f : 1.0f;  // log2(e)/sqrt(4096)
#pragma unroll
    for (int ft = 0; ft < 4; ++ft)
#pragma unroll
      for (int r = 0; r < 4; ++r)
        O[(gr0 + rowbase + 4 * hi + r) * DOUT + ft * 16 + l15] = f2bf(acc[ft][r] * qs);
  } else {
    const size_t b     = gr0 >> 12;       // / 4096
    const size_t sbase = gr0 & 4095;      // 64-aligned within batch
#pragma unroll
    for (int ft = 0; ft < 4; ++ft) {
      const int n = ft * 16 + l15;
      ushort* dst = Vt + (b * DOUT + n) * S_LEN + sbase;
#pragma unroll
      for (int r = 0; r < 4; ++r) {
        const int s = rowbase + 4 * hi + r;                        // 0..63 original key
        const int slot = (s & 0x23) | ((s & 0x10) >> 2) | ((s & 0x0C) << 1);  // sigma^-1 (within each 32)
        dst[slot] = f2bf(acc[ft][r]);
      }
    }
  }
}

// ---------------- flash attention: paired q-chunks, vote-gated softmax, no common-path ds ops ----
// grid (128, B), 512 threads = 8 waves. Block handles chunks c1=255-bx (heavy, nh waves)
// and c0=bx (light, 8-nh waves). Each group stripes its chunk's KV tiles.
__global__ __launch_bounds__(512, 4) void attn_kernel(
    const ushort* __restrict__ Qb, const ushort* __restrict__ Kb,
    const ushort* __restrict__ Vt, float* __restrict__ Out)
{
  __shared__ float mbuf[8][16];
  __shared__ float lbuf[8][16];
  __shared__ float obuf[8][16][64];

  const int tid  = threadIdx.x;
  const int lane = tid & 63;
  const int w    = tid >> 6;           // 0..7
  const int l15  = lane & 15;
  const int hi   = lane >> 4;          // 0..3
  const int b    = blockIdx.y;
  const int bx   = blockIdx.x;         // 0..127

  const int c1  = 255 - bx;            // heavy chunk
  const int c0  = bx;                  // light chunk
  const int nt1 = c1 / 2 + 1;          // KV tiles for heavy
  const int nt0 = c0 / 2 + 1;
  int nh = (8 * nt1 + ((nt1 + nt0) >> 1)) / (nt1 + nt0);   // waves for heavy, rounded
  nh = nh < 1 ? 1 : (nh > 7 ? 7 : nh);

  const bool heavy  = (w < nh);
  const int chunk   = heavy ? c1 : c0;
  const int qbase   = chunk * 16;
  const int ws      = heavy ? w : (w - nh);
  const int step    = heavy ? nh : (8 - nh);
  const int ntiles  = heavy ? nt1 : nt0;

  // Q as B-operand fragments (pre-scaled by log2e/64): col=q=l15, depth=8*hi..+7
  const ushort* Qp = Qb + ((size_t)b * S_LEN + qbase + l15) * DOUT + hi * 8;
  short8 qB0 = *(const short8*)Qp;
  short8 qB1 = *(const short8*)(Qp + 32);

  float m = -INFINITY, l = 0.f;        // per-lane state; l is a PARTIAL sum (lane's keys only)
  f32x4 acc[4];                        // O[q=4hi+r][dout=ft*16+l15]
#pragma unroll
  for (int ft = 0; ft < 4; ++ft) acc[ft] = (f32x4){0.f, 0.f, 0.f, 0.f};

  const ushort* Kbase = Kb + (size_t)b * S_LEN * DOUT;
  const ushort* Vbase = Vt + (size_t)b * DOUT * S_LEN;
  const int qg = qbase + l15;

  // prologue: load K for this wave's first tile (safe address even if idle)
  short8 ka[2][2];
  {
    const int kv0 = ws * KB;
#pragma unroll
    for (int sub = 0; sub < 2; ++sub) {
      const ushort* kp = Kbase + (size_t)(kv0 + sub * 16 + l15) * DOUT + hi * 8;
      ka[sub][0] = *(const short8*)kp;
      ka[sub][1] = *(const short8*)(kp + 32);
    }
  }

  for (int t = ws; t < ntiles; t += step) {
    const int kv = t * KB;
    // --- V loads for current tile (cover latency with QK+softmax) ---
    short8 vb[4];
#pragma unroll
    for (int ft = 0; ft < 4; ++ft)
      vb[ft] = *(const short8*)(Vbase + (size_t)(ft * 16 + l15) * S_LEN + kv + hi * 8);
    // --- K prefetch for next stripe tile ---
    const int tn = (t + step < ntiles) ? (t + step) : t;
    const int kvn = tn * KB;
    short8 kn[2][2];
#pragma unroll
    for (int sub = 0; sub < 2; ++sub) {
      const ushort* kp = Kbase + (size_t)(kvn + sub * 16 + l15) * DOUT + hi * 8;
      kn[sub][0] = *(const short8*)kp;
      kn[sub][1] = *(const short8*)(kp + 32);
    }
    // --- QK^T swapped: A=K, B=Q -> C[key][q] ---
    float p[2][4];                     // p[sub][r]: key = kv+16*sub+4*hi+r, q = l15
#pragma unroll
    for (int sub = 0; sub < 2; ++sub) {
      f32x4 s = (f32x4){0.f, 0.f, 0.f, 0.f};
      s = __builtin_amdgcn_mfma_f32_16x16x32_bf16(ka[sub][0], qB0, s, 0, 0, 0);
      s = __builtin_amdgcn_mfma_f32_16x16x32_bf16(ka[sub][1], qB1, s, 0, 0, 0);
#pragma unroll
      for (int r = 0; r < 4; ++r) p[sub][r] = s[r];
    }
    // --- causal mask: only the diagonal tile ---
    if (t == ntiles - 1) {
#pragma unroll
      for (int sub = 0; sub < 2; ++sub)
#pragma unroll
        for (int r = 0; r < 4; ++r) {
          const int kg = kv + sub * 16 + 4 * hi + r;
          if (kg > qg) p[sub][r] = -INFINITY;
        }
    }
    // --- per-lane max; wave-wide vote gates the (rare) rescale ---
    float tm = p[0][0];
#pragma unroll
    for (int sub = 0; sub < 2; ++sub)
#pragma unroll
      for (int r = 0; r < 4; ++r) tm = fmaxf(tm, p[sub][r]);
    if (!__all(tm <= m + 8.0f)) {      // uniform branch
      float tr = fmaxf(tm, __shfl_xor(tm, 16, 64));
      tr = fmaxf(tr, __shfl_xor(tr, 32, 64));     // row max (q = l15)
      const float mn = fmaxf(m, tr);
      const float sf = exp2f(m - mn);  // m=-inf -> 0
      m = mn;
      l *= sf;
      float sfr[4];
#pragma unroll
      for (int r = 0; r < 4; ++r) sfr[r] = __shfl(sf, 4 * hi + r, 64);
#pragma unroll
      for (int ft = 0; ft < 4; ++ft)
#pragma unroll
        for (int r = 0; r < 4; ++r) acc[ft][r] *= sfr[r];
    }
    // --- P = exp2(s - m); accumulate PARTIAL row sum in-lane (no shuffles) ---
    float rs = 0.f;
    ushort pk[8];
#pragma unroll
    for (int sub = 0; sub < 2; ++sub)
#pragma unroll
      for (int r = 0; r < 4; ++r) {
        const float e = exp2f(p[sub][r] - m);
        pk[sub * 4 + r] = f2bf(e);
        rs += e;
      }
    l += rs;
    short8 pa = *(short8*)pk;
    // --- PV: A=P[q][slot], B=V_perm[slot][dout] ---
#pragma unroll
    for (int ft = 0; ft < 4; ++ft)
      acc[ft] = __builtin_amdgcn_mfma_f32_16x16x32_bf16(pa, vb[ft], acc[ft], 0, 0, 0);
    // --- rotate prefetched K ---
#pragma unroll
    for (int sub = 0; sub < 2; ++sub) {
      ka[sub][0] = kn[sub][0];
      ka[sub][1] = kn[sub][1];
    }
  }

  // --- one-time reduce of the partial row sum across the hi-group ---
  l += __shfl_xor(l, 16, 64);
  l += __shfl_xor(l, 32, 64);
  if (lane < 16) { mbuf[w][lane] = m; lbuf[w][lane] = l; }
#pragma unroll
  for (int ft = 0; ft < 4; ++ft)
#pragma unroll
    for (int r = 0; r < 4; ++r)
      obuf[w][4 * hi + r][ft * 16 + l15] = acc[ft][r];
  __syncthreads();

  // --- merge: tid<256 -> heavy chunk (waves [0,nh)), tid>=256 -> light (waves [nh,8)) ---
  const int g   = tid >> 8;
  const int rt  = tid & 255;
  const int row = rt >> 4;
  const int cs  = (rt & 15) * 4;
  const int lo  = g ? nh : 0;
  const int hiW = g ? 8 : nh;
  const int qb  = (g ? c0 : c1) * 16;

  float M = -INFINITY;
  for (int i = lo; i < hiW; ++i) M = fmaxf(M, mbuf[i][row]);
  float L = 0.f;
  float4 o = (float4){0.f, 0.f, 0.f, 0.f};
  for (int i = lo; i < hiW; ++i) {
    const float e = exp2f(mbuf[i][row] - M);
    L += lbuf[i][row] * e;
    o.x += obuf[i][row][cs + 0] * e;
    o.y += obuf[i][row][cs + 1] * e;
    o.z += obuf[i][row][cs + 2] * e;
    o.w += obuf[i][row][cs + 3] * e;
  }
  const float inv = 1.f / L;
  o.x *= inv; o.y *= inv; o.z *= inv; o.w *= inv;
  *(float4*)(Out + ((size_t)b * S_LEN + qb + row) * DOUT + cs) = o;
}

extern "C" void kernel_launch(void* const* d_in, const int* in_sizes, int n_in,
                              void* d_out, int out_size, void* d_ws, size_t ws_size,
                              hipStream_t stream) {
  const float* Xk = (const float*)d_in[0];
  const float* Xv = (const float*)d_in[1];
  const float* Xq = (const float*)d_in[2];
  const float* Wk = (const float*)d_in[3];
  const float* Wv = (const float*)d_in[4];
  const float* Wq = (const float*)d_in[5];
  float* Out = (float*)d_out;

  ushort* Kb = (ushort*)d_ws;                               // [B][S][64] bf16
  ushort* Qb = Kb + (size_t)NBATCH * S_LEN * DOUT;          // [B][S][64] bf16 (pre-scaled)
  ushort* Vt = Qb + (size_t)NBATCH * S_LEN * DOUT;          // [B][64][S] bf16, sigma-permuted

  proj_kernel<<<dim3(NBATCH * S_LEN / 64, 3), 256, 0, stream>>>(
      Xk, Wk, Kb, Xq, Wq, Qb, Xv, Wv, Vt);
  // 4096 rows / (2 chunks x 16 rows per block) = 128 blocks in x  (R12 bug: was /32/4 = 32)
  attn_kernel<<<dim3(S_LEN / 32, NBATCH), 512, 0, stream>>>(Qb, Kb, Vt, Out);
}